// Round 4
// baseline (1714.447 us; speedup 1.0000x reference)
//
#include <hip/hip_runtime.h>

typedef unsigned short u16;
typedef unsigned int   u32;
typedef __attribute__((ext_vector_type(4))) float f32x4;
typedef __attribute__((ext_vector_type(8))) short bf16x8;

#define NG 64
#define BSH 7          // 128 nodes per bucket
#define BCAP 5120      // LDS staging capacity (edges); Poisson(4096) max ~4450, 8-sigma margin
#define PAD 16         // ints per counter (one 64B line) to kill same-line atomic serialization

__device__ __forceinline__ u16 f2bf(float f){
  u32 u = __float_as_uint(f);
  u += 0x7fffu + ((u >> 16) & 1u);   // RNE
  return (u16)(u >> 16);
}
__device__ __forceinline__ float bflo(u32 p){ return __uint_as_float(p << 16); }
__device__ __forceinline__ float bfhi(u32 p){ return __uint_as_float(p & 0xffff0000u); }

// ---------------- K1: bucket histogram (LDS pre-aggregated) ----------------
__global__ void bhist_kernel(const int* __restrict__ ei, int* __restrict__ bhist,
                             int E, int NBK){
  __shared__ int h[1024];
  int t = threadIdx.x;
  for (int b = t; b < 1024; b += 256) h[b] = 0;
  __syncthreads();
  for (int e = blockIdx.x * 256 + t; e < E; e += gridDim.x * 256)
    atomicAdd(&h[ei[E + e] >> BSH], 1);
  __syncthreads();
  for (int b = t; b < NBK; b += 256){
    int v = h[b];
    if (v) atomicAdd(&bhist[b * PAD], v);
  }
}

// ---------------- K2: scan bucket counts -> bases/cursors; rowptr[N]=E ----------------
__global__ void bscan_kernel(const int* __restrict__ bhist, int* __restrict__ bbase,
                             int* __restrict__ gcur, int* __restrict__ rowptr,
                             int NBK, int E, int N){
  __shared__ int sh[256];
  int t = threadIdx.x;
  int base = t * 4;
  int v[4]; int s = 0;
  #pragma unroll
  for (int j = 0; j < 4; ++j){
    int idx = base + j;
    v[j] = (idx < NBK) ? bhist[idx * PAD] : 0;
    s += v[j];
  }
  sh[t] = s; __syncthreads();
  for (int off = 1; off < 256; off <<= 1){
    int x = sh[t]; int y = (t >= off) ? sh[t - off] : 0;
    __syncthreads(); sh[t] = x + y; __syncthreads();
  }
  int run = sh[t] - s;
  #pragma unroll
  for (int j = 0; j < 4; ++j){
    int idx = base + j;
    if (idx <= NBK){ bbase[idx * PAD] = run; gcur[idx * PAD] = run; }
    run += v[j];
  }
  if (t == 0) rowptr[N] = E;
}

// ---------------- K3: bin edges into bucket-contiguous mid[] = (src, dst) ----------------
__global__ void bin_kernel(const int* __restrict__ ei, int* __restrict__ gcur,
                           int2* __restrict__ mid, int E, int NBK){
  __shared__ int hist[1024];
  __shared__ int base[1024];
  int t = threadIdx.x;
  int e0 = blockIdx.x * 8192;
  int mysrc[32], mydst[32];
  for (int b = t; b < 1024; b += 256) hist[b] = 0;
  __syncthreads();
  #pragma unroll
  for (int i = 0; i < 32; ++i){
    int e = e0 + i * 256 + t;
    int d = -1, sv = 0;
    if (e < E){ d = ei[E + e]; sv = ei[e]; atomicAdd(&hist[d >> BSH], 1); }
    mydst[i] = d; mysrc[i] = sv;
  }
  __syncthreads();
  for (int b = t; b < NBK; b += 256){
    int hh = hist[b];
    if (hh) base[b] = atomicAdd(&gcur[b * PAD], hh);
  }
  __syncthreads();
  #pragma unroll
  for (int i = 0; i < 32; ++i){
    int d = mydst[i];
    if (d >= 0){
      int p = atomicAdd(&base[d >> BSH], 1);
      mid[p] = make_int2(mysrc[i], d);
    }
  }
}

// ---------------- K4a: per-bucket node degrees -> rowptr, dinv ----------------
__global__ void nodestat_kernel(const int2* __restrict__ mid, const int* __restrict__ bbase,
                                int* __restrict__ rowptr, float* __restrict__ dinv, int N){
  __shared__ int hist[128];
  __shared__ int sh[128];
  int b = blockIdx.x, t = threadIdx.x;
  int e0 = bbase[b * PAD], e1 = bbase[(b + 1) * PAD];
  if (t < 128) hist[t] = 0;
  __syncthreads();
  for (int i = e0 + t; i < e1; i += 256) atomicAdd(&hist[mid[i].y & 127], 1);
  __syncthreads();
  int val = (t < 128) ? hist[t] : 0;
  if (t < 128) sh[t] = val;
  __syncthreads();
  for (int off = 1; off < 128; off <<= 1){
    int x = 0;
    if (t < 128){ x = sh[t]; if (t >= off) x += sh[t - off]; }
    __syncthreads();
    if (t < 128) sh[t] = x;
    __syncthreads();
  }
  if (t < 128){
    int n = b * 128 + t;
    if (n < N){
      rowptr[n] = e0 + sh[t] - val;          // exclusive prefix within bucket
      dinv[n] = rsqrtf((float)val + 1.0f);
    }
  }
}

// ---------------- K4b: per-bucket LDS scatter -> final src stream, coalesced ----------------
__global__ __launch_bounds__(256)
void scatter_kernel(const int2* __restrict__ mid, const int* __restrict__ bbase,
                    const int* __restrict__ rowptr,
                    int* __restrict__ fin, int N){
  __shared__ int cur[128];
  __shared__ int stg[BCAP];
  int b = blockIdx.x, t = threadIdx.x;
  int e0 = bbase[b * PAD], e1 = bbase[(b + 1) * PAD];
  int sz = e1 - e0;
  if (t < 128){
    int n = b * 128 + t;
    cur[t] = ((n < N) ? rowptr[n] : e1) - e0;
  }
  __syncthreads();
  if (sz <= BCAP){
    for (int i = e0 + t; i < e1; i += 256){
      int2 m = mid[i];
      int p = atomicAdd(&cur[m.y & 127], 1);
      stg[p] = m.x;
    }
    __syncthreads();
    for (int j = t; j < sz; j += 256) fin[e0 + j] = stg[j];
  } else {
    // statistically unreachable overflow fallback: direct (uncoalesced) scatter
    for (int i = e0 + t; i < e1; i += 256){
      int2 m = mid[i];
      int p = atomicAdd(&cur[m.y & 127], 1);
      fin[e0 + p] = m.x;
    }
  }
}

// ---------------- weight convert + transpose to bf16 [n][k] ----------------
__global__ void wcvt_kernel(const float* __restrict__ W1, const float* __restrict__ W2,
                            u16* __restrict__ W1T, u16* __restrict__ W2T){
  int i = blockIdx.x * 256 + threadIdx.x;
  if (i < 512 * 128){ int k = i >> 7, n = i & 127; W1T[(size_t)n * 512 + k] = f2bf(W1[i]); }
  if (i < 128 * 128){ int k = i >> 7, n = i & 127; W2T[(size_t)n * 128 + k] = f2bf(W2[i]); }
}

// ---------------- MFMA GEMM: [N,K] @ [K,128] -> bf16 [N,128] (no bias) ----------------
template<int A_BF16>
__global__ __launch_bounds__(256, 3)
void gemm_kernel(const void* __restrict__ Ap, const u16* __restrict__ BT,
                 u16* __restrict__ C, int N, int K)
{
  constexpr int LDA = 40;
  __shared__ __align__(16) u16 As[128 * LDA];
  __shared__ __align__(16) u16 Bs[128 * LDA];
  const int t = threadIdx.x;
  const int wave = t >> 6, lane = t & 63;
  const int q = lane >> 4, r = lane & 15;
  const int row0 = blockIdx.x * 128;
  f32x4 zero = {0.f, 0.f, 0.f, 0.f};
  f32x4 acc[2][8];
  #pragma unroll
  for (int i = 0; i < 2; ++i)
    #pragma unroll
    for (int j = 0; j < 8; ++j) acc[i][j] = zero;

  for (int k0 = 0; k0 < K; k0 += 32){
    {
      int rr = t >> 2, cc = (t & 3) * 8;
      #pragma unroll
      for (int it = 0; it < 2; ++it){
        int n = rr + it * 64;
        uint4 v = *(const uint4*)(BT + (size_t)n * K + k0 + cc);
        *(uint4*)(&Bs[n * LDA + cc]) = v;
      }
    }
    if (A_BF16){
      const u16* A = (const u16*)Ap;
      int rr = t >> 2, cc = (t & 3) * 8;
      #pragma unroll
      for (int it = 0; it < 2; ++it){
        int rl = rr + it * 64, row = row0 + rl;
        uint4 v = make_uint4(0u, 0u, 0u, 0u);
        if (row < N) v = *(const uint4*)(A + (size_t)row * K + k0 + cc);
        *(uint4*)(&As[rl * LDA + cc]) = v;
      }
    } else {
      const float* A = (const float*)Ap;
      int rr = t >> 3, cc = (t & 7) * 4;
      #pragma unroll
      for (int it = 0; it < 4; ++it){
        int rl = rr + it * 32, row = row0 + rl;
        float4 v = make_float4(0.f, 0.f, 0.f, 0.f);
        if (row < N) v = *(const float4*)(A + (size_t)row * K + k0 + cc);
        uint2 p;
        p.x = (u32)f2bf(v.x) | ((u32)f2bf(v.y) << 16);
        p.y = (u32)f2bf(v.z) | ((u32)f2bf(v.w) << 16);
        *(uint2*)(&As[rl * LDA + cc]) = p;
      }
    }
    __syncthreads();
    bf16x8 af[2], bfr[8];
    #pragma unroll
    for (int rt = 0; rt < 2; ++rt)
      af[rt] = *(const bf16x8*)(&As[(wave * 32 + rt * 16 + r) * LDA + q * 8]);
    #pragma unroll
    for (int ct = 0; ct < 8; ++ct)
      bfr[ct] = *(const bf16x8*)(&Bs[(ct * 16 + r) * LDA + q * 8]);
    #pragma unroll
    for (int rt = 0; rt < 2; ++rt)
      #pragma unroll
      for (int ct = 0; ct < 8; ++ct)
        acc[rt][ct] = __builtin_amdgcn_mfma_f32_16x16x32_bf16(af[rt], bfr[ct], acc[rt][ct], 0, 0, 0);
    __syncthreads();
  }
  #pragma unroll
  for (int rt = 0; rt < 2; ++rt)
    #pragma unroll
    for (int reg = 0; reg < 4; ++reg){
      int row = row0 + wave * 32 + rt * 16 + q * 4 + reg;
      if (row < N)
        #pragma unroll
        for (int ct = 0; ct < 8; ++ct)
          C[(size_t)row * 128 + ct * 16 + r] = f2bf(acc[rt][ct][reg]);
    }
}

// ---------------- feature-sliced edge aggregation ----------------
// 8 slices x 16 feats. Wave = 1 node; 64 lanes = 8 edge-groups x 8 u32-lanes.
// Per slice the 3.2 MB h-slice is L2-resident (blocks of one slice run
// together: slice = blockIdx / nodeBlocks). Cross-group shfl_xor reduction.
__global__ __launch_bounds__(256)
void agg_kernel(const u16* __restrict__ h, const int* __restrict__ srcs,
                const int* __restrict__ rowptr, const float* __restrict__ dinv,
                const float* __restrict__ bias, u16* __restrict__ out,
                int N, int nodeBlocks)
{
  int slice = blockIdx.x / nodeBlocks;
  int nb    = blockIdx.x - slice * nodeBlocks;
  int node  = nb * 4 + (int)(threadIdx.x >> 6);
  if (node >= N) return;
  const int lane = threadIdx.x & 63;
  const int grp = lane >> 3;          // edge group 0..7
  const int sub = lane & 7;           // u32 within 32B slice chunk
  const int sOff = slice * 8 + sub;   // u32 offset within 64-u32 row
  const u32* __restrict__ hp = (const u32*)h;
  int beg = rowptr[node], end = rowptr[node + 1];

  float ax = 0.f, ay = 0.f;
  if (beg < end){
    // pipeline: src/w one step ahead
    int e = beg + grp;
    int srcCur = __builtin_nontemporal_load(&srcs[e < end ? e : end - 1]);
    float wCur = (e < end) ? dinv[srcCur] : 0.f;
    for (int base = beg; base < end; base += 8){
      int en = base + 8 + grp;
      int srcNxt = 0;
      bool more = (base + 8 < end);
      if (more) srcNxt = __builtin_nontemporal_load(&srcs[en < end ? en : end - 1]);
      u32 v = hp[(size_t)srcCur * 64 + sOff];          // L2-resident slice gather
      float wNxt = (more && en < end) ? dinv[srcNxt] : 0.f;
      ax = fmaf(wCur, bflo(v), ax);
      ay = fmaf(wCur, bfhi(v), ay);
      srcCur = srcNxt; wCur = wNxt;
    }
  }
  // reduce the 8 edge-groups (lanes with equal sub)
  #pragma unroll
  for (int off = 8; off < 64; off <<= 1){
    ax += __shfl_xor(ax, off, 64);
    ay += __shfl_xor(ay, off, 64);
  }
  if (grp == 0){
    float dv = dinv[node], dv2 = dv * dv;
    u32 hs = hp[(size_t)node * 64 + sOff];
    float b0 = bias[sOff * 2 + 0], b1v = bias[sOff * 2 + 1];
    ax = fmaf(dv, ax, fmaf(dv2, bflo(hs), b0));
    ay = fmaf(dv, ay, fmaf(dv2, bfhi(hs), b1v));
    ax = fmaxf(ax, 0.f); ay = fmaxf(ay, 0.f);
    u32 pk = (u32)f2bf(ax) | ((u32)f2bf(ay) << 16);
    __builtin_nontemporal_store(pk, (u32*)out + (size_t)node * 64 + sOff);
  }
}

// ---------------- per-graph max pool ----------------
__global__ void pool_kernel(const u16* __restrict__ h, const int* __restrict__ batch,
                            float* __restrict__ g, int N)
{
  int graph = blockIdx.x >> 3, chunk = blockIdx.x & 7;
  int f = threadIdx.x;
  int lo = 0, hi = N;
  while (lo < hi){ int mid = (lo + hi) >> 1; if (batch[mid] < graph) lo = mid + 1; else hi = mid; }
  int s = lo;
  hi = N;
  while (lo < hi){ int mid = (lo + hi) >> 1; if (batch[mid] < graph + 1) lo = mid + 1; else hi = mid; }
  int epos = lo;
  int len = epos - s;
  if (len <= 0) return;
  int per = (len + 7) >> 3;
  int a = s + chunk * per;
  int b = a + per; if (b > epos) b = epos;
  float m = 0.f;
  for (int n = a; n < b; ++n)
    m = fmaxf(m, __uint_as_float(((u32)h[(size_t)n * 128 + f]) << 16));
  if (a < b) atomicMax((int*)&g[graph * 128 + f], __float_as_int(m));
}

// ---------------- head ----------------
__global__ void head_kernel(const float* __restrict__ g, const float* __restrict__ Wc,
                            const float* __restrict__ bc, float* __restrict__ out)
{
  int gg = threadIdx.x;
  if (gg >= NG) return;
  float l0 = bc[0], l1 = bc[1];
  for (int f = 0; f < 128; ++f){
    float v = g[gg * 128 + f];
    l0 = fmaf(v, Wc[f * 2 + 0], l0);
    l1 = fmaf(v, Wc[f * 2 + 1], l1);
  }
  float m = fmaxf(l0, l1);
  float lse = m + logf(__expf(l0 - m) + __expf(l1 - m));
  out[gg * 2 + 0] = l0 - lse;
  out[gg * 2 + 1] = l1 - lse;
}

extern "C" void kernel_launch(void* const* d_in, const int* in_sizes, int n_in,
                              void* d_out, int out_size, void* d_ws, size_t ws_size,
                              hipStream_t stream)
{
  const float* x   = (const float*)d_in[0];
  const int*   ei  = (const int*)  d_in[1];
  const int*  batch= (const int*)  d_in[2];
  const float* W1  = (const float*)d_in[3];
  const float* b1  = (const float*)d_in[4];
  const float* W2  = (const float*)d_in[5];
  const float* b2  = (const float*)d_in[6];
  const float* Wc  = (const float*)d_in[7];
  const float* bc  = (const float*)d_in[8];
  float* out = (float*)d_out;
  (void)n_in; (void)out_size; (void)ws_size;

  const int N = in_sizes[0] / 512;
  const int E = in_sizes[1] / 2;
  const int NBK = (N + 127) >> 7;

  char* w = (char*)d_ws;
  size_t o = 0;
  auto take = [&](size_t bytes)->char* {
    char* p = w + o; o = (o + bytes + 511) & ~(size_t)511; return p;
  };
  size_t hbytes = (size_t)N * 128 * 2;
  size_t mbytes = (size_t)E * 8;
  int*   bhist  = (int*)  take((size_t)(NBK + 2) * PAD * 4);
  int*   bbase  = (int*)  take((size_t)(NBK + 2) * PAD * 4);
  int*   gcur   = (int*)  take((size_t)(NBK + 2) * PAD * 4);
  int*   rowptr = (int*)  take((size_t)(N + 1) * 4);
  float* dinv   = (float*)take((size_t)N * 4);
  int*   fin    = (int*)  take((size_t)E * 4);
  u16*   W1T    = (u16*)  take((size_t)512 * 128 * 2);
  u16*   W2T    = (u16*)  take((size_t)128 * 128 * 2);
  u16*   hA     = (u16*)  take(hbytes > mbytes ? hbytes : mbytes);
  u16*   hB     = (u16*)  take(hbytes);
  float* gpool  = (float*)take((size_t)NG * 128 * 4);
  int2*  mid    = (int2*)hA;   // mid dead before gemm1 writes hA

  hipMemsetAsync(bhist, 0, (size_t)(NBK + 2) * PAD * 4, stream);
  hipMemsetAsync(gpool, 0, (size_t)NG * 128 * 4, stream);

  bhist_kernel<<<256, 256, 0, stream>>>(ei, bhist, E, NBK);
  bscan_kernel<<<1, 256, 0, stream>>>(bhist, bbase, gcur, rowptr, NBK, E, N);
  bin_kernel<<<(E + 8191) / 8192, 256, 0, stream>>>(ei, gcur, mid, E, NBK);
  nodestat_kernel<<<NBK, 256, 0, stream>>>(mid, bbase, rowptr, dinv, N);
  scatter_kernel<<<NBK, 256, 0, stream>>>(mid, bbase, rowptr, fin, N);
  wcvt_kernel<<<256, 256, 0, stream>>>(W1, W2, W1T, W2T);

  const int GB = (N + 127) / 128;
  const int nodeBlocks = (N + 3) / 4;
  gemm_kernel<0><<<GB, 256, 0, stream>>>((const void*)x,  W1T, hA, N, 512);
  agg_kernel<<<8 * nodeBlocks, 256, 0, stream>>>(hA, fin, rowptr, dinv, b1, hB, N, nodeBlocks);
  gemm_kernel<1><<<GB, 256, 0, stream>>>((const void*)hB, W2T, hA, N, 128);
  agg_kernel<<<8 * nodeBlocks, 256, 0, stream>>>(hA, fin, rowptr, dinv, b2, hB, N, nodeBlocks);
  pool_kernel<<<NG * 8, 128, 0, stream>>>(hB, batch, gpool, N);
  head_kernel<<<1, 64, 0, stream>>>(gpool, Wc, bc, out);
}

// Round 5
// 1523.467 us; speedup vs baseline: 1.1254x; 1.1254x over previous
//
#include <hip/hip_runtime.h>

typedef unsigned short u16;
typedef unsigned int   u32;
typedef __attribute__((ext_vector_type(4))) float f32x4;
typedef __attribute__((ext_vector_type(8))) short bf16x8;

#define NG 64
#define BSH 7          // 128 nodes per bucket
#define BCAP 5120      // LDS staging capacity (edges); Poisson(4096) max ~4450, 8-sigma margin
#define PAD 16         // ints per counter (one 64B line) to kill same-line atomic serialization

__device__ __forceinline__ u16 f2bf(float f){
  u32 u = __float_as_uint(f);
  u += 0x7fffu + ((u >> 16) & 1u);   // RNE
  return (u16)(u >> 16);
}
__device__ __forceinline__ float bflo(u32 p){ return __uint_as_float(p << 16); }
__device__ __forceinline__ float bfhi(u32 p){ return __uint_as_float(p & 0xffff0000u); }

// h layout is SLICE-MAJOR: [8 slices][N nodes][16 feats] u16.
// Slice s = feats [16s,16s+16). One slice = 3.2 MB contiguous -> L2-resident.

// ---------------- K1: bucket histogram (LDS pre-aggregated) ----------------
__global__ void bhist_kernel(const int* __restrict__ ei, int* __restrict__ bhist,
                             int E, int NBK){
  __shared__ int h[1024];
  int t = threadIdx.x;
  for (int b = t; b < 1024; b += 256) h[b] = 0;
  __syncthreads();
  for (int e = blockIdx.x * 256 + t; e < E; e += gridDim.x * 256)
    atomicAdd(&h[ei[E + e] >> BSH], 1);
  __syncthreads();
  for (int b = t; b < NBK; b += 256){
    int v = h[b];
    if (v) atomicAdd(&bhist[b * PAD], v);
  }
}

// ---------------- K2: scan bucket counts -> bases/cursors; rowptr[N]=E ----------------
__global__ void bscan_kernel(const int* __restrict__ bhist, int* __restrict__ bbase,
                             int* __restrict__ gcur, int* __restrict__ rowptr,
                             int NBK, int E, int N){
  __shared__ int sh[256];
  int t = threadIdx.x;
  int base = t * 4;
  int v[4]; int s = 0;
  #pragma unroll
  for (int j = 0; j < 4; ++j){
    int idx = base + j;
    v[j] = (idx < NBK) ? bhist[idx * PAD] : 0;
    s += v[j];
  }
  sh[t] = s; __syncthreads();
  for (int off = 1; off < 256; off <<= 1){
    int x = sh[t]; int y = (t >= off) ? sh[t - off] : 0;
    __syncthreads(); sh[t] = x + y; __syncthreads();
  }
  int run = sh[t] - s;
  #pragma unroll
  for (int j = 0; j < 4; ++j){
    int idx = base + j;
    if (idx <= NBK){ bbase[idx * PAD] = run; gcur[idx * PAD] = run; }
    run += v[j];
  }
  if (t == 0) rowptr[N] = E;
}

// ---------------- K3: bin edges into bucket-contiguous mid[] = (src, dst) ----------------
__global__ void bin_kernel(const int* __restrict__ ei, int* __restrict__ gcur,
                           int2* __restrict__ mid, int E, int NBK){
  __shared__ int hist[1024];
  __shared__ int base[1024];
  int t = threadIdx.x;
  int e0 = blockIdx.x * 8192;
  int mysrc[32], mydst[32];
  for (int b = t; b < 1024; b += 256) hist[b] = 0;
  __syncthreads();
  #pragma unroll
  for (int i = 0; i < 32; ++i){
    int e = e0 + i * 256 + t;
    int d = -1, sv = 0;
    if (e < E){ d = ei[E + e]; sv = ei[e]; atomicAdd(&hist[d >> BSH], 1); }
    mydst[i] = d; mysrc[i] = sv;
  }
  __syncthreads();
  for (int b = t; b < NBK; b += 256){
    int hh = hist[b];
    if (hh) base[b] = atomicAdd(&gcur[b * PAD], hh);
  }
  __syncthreads();
  #pragma unroll
  for (int i = 0; i < 32; ++i){
    int d = mydst[i];
    if (d >= 0){
      int p = atomicAdd(&base[d >> BSH], 1);
      mid[p] = make_int2(mysrc[i], d);
    }
  }
}

// ---------------- K4a: per-bucket node degrees -> rowptr, dinv ----------------
__global__ void nodestat_kernel(const int2* __restrict__ mid, const int* __restrict__ bbase,
                                int* __restrict__ rowptr, float* __restrict__ dinv, int N){
  __shared__ int hist[128];
  __shared__ int sh[128];
  int b = blockIdx.x, t = threadIdx.x;
  int e0 = bbase[b * PAD], e1 = bbase[(b + 1) * PAD];
  if (t < 128) hist[t] = 0;
  __syncthreads();
  for (int i = e0 + t; i < e1; i += 256) atomicAdd(&hist[mid[i].y & 127], 1);
  __syncthreads();
  int val = (t < 128) ? hist[t] : 0;
  if (t < 128) sh[t] = val;
  __syncthreads();
  for (int off = 1; off < 128; off <<= 1){
    int x = 0;
    if (t < 128){ x = sh[t]; if (t >= off) x += sh[t - off]; }
    __syncthreads();
    if (t < 128) sh[t] = x;
    __syncthreads();
  }
  if (t < 128){
    int n = b * 128 + t;
    if (n < N){
      rowptr[n] = e0 + sh[t] - val;          // exclusive prefix within bucket
      dinv[n] = rsqrtf((float)val + 1.0f);
    }
  }
}

// ---------------- K4b: per-bucket LDS scatter -> final src stream, coalesced ----------------
__global__ __launch_bounds__(256)
void scatter_kernel(const int2* __restrict__ mid, const int* __restrict__ bbase,
                    const int* __restrict__ rowptr,
                    int* __restrict__ fin, int N){
  __shared__ int cur[128];
  __shared__ int stg[BCAP];
  int b = blockIdx.x, t = threadIdx.x;
  int e0 = bbase[b * PAD], e1 = bbase[(b + 1) * PAD];
  int sz = e1 - e0;
  if (t < 128){
    int n = b * 128 + t;
    cur[t] = ((n < N) ? rowptr[n] : e1) - e0;
  }
  __syncthreads();
  if (sz <= BCAP){
    for (int i = e0 + t; i < e1; i += 256){
      int2 m = mid[i];
      int p = atomicAdd(&cur[m.y & 127], 1);
      stg[p] = m.x;
    }
    __syncthreads();
    for (int j = t; j < sz; j += 256) fin[e0 + j] = stg[j];
  } else {
    // statistically unreachable overflow fallback: direct (uncoalesced) scatter
    for (int i = e0 + t; i < e1; i += 256){
      int2 m = mid[i];
      int p = atomicAdd(&cur[m.y & 127], 1);
      fin[e0 + p] = m.x;
    }
  }
}

// ---------------- weight convert + transpose to bf16 [n][k] ----------------
__global__ void wcvt_kernel(const float* __restrict__ W1, const float* __restrict__ W2,
                            u16* __restrict__ W1T, u16* __restrict__ W2T){
  int i = blockIdx.x * 256 + threadIdx.x;
  if (i < 512 * 128){ int k = i >> 7, n = i & 127; W1T[(size_t)n * 512 + k] = f2bf(W1[i]); }
  if (i < 128 * 128){ int k = i >> 7, n = i & 127; W2T[(size_t)n * 128 + k] = f2bf(W2[i]); }
}

// ---------------- MFMA GEMM: [N,K] @ [K,128] -> bf16 slice-major [8][N][16] ----------------
// A_BF16=0: A is row-major fp32 [N][K]. A_BF16=1: A is slice-major bf16 [8][N][16] (K=128).
template<int A_BF16>
__global__ __launch_bounds__(256, 3)
void gemm_kernel(const void* __restrict__ Ap, const u16* __restrict__ BT,
                 u16* __restrict__ C, int N, int K)
{
  constexpr int LDA = 40;
  __shared__ __align__(16) u16 As[128 * LDA];
  __shared__ __align__(16) u16 Bs[128 * LDA];
  const int t = threadIdx.x;
  const int wave = t >> 6, lane = t & 63;
  const int q = lane >> 4, r = lane & 15;
  const int row0 = blockIdx.x * 128;
  f32x4 zero = {0.f, 0.f, 0.f, 0.f};
  f32x4 acc[2][8];
  #pragma unroll
  for (int i = 0; i < 2; ++i)
    #pragma unroll
    for (int j = 0; j < 8; ++j) acc[i][j] = zero;

  for (int k0 = 0; k0 < K; k0 += 32){
    {
      int rr = t >> 2, cc = (t & 3) * 8;
      #pragma unroll
      for (int it = 0; it < 2; ++it){
        int n = rr + it * 64;
        uint4 v = *(const uint4*)(BT + (size_t)n * K + k0 + cc);
        *(uint4*)(&Bs[n * LDA + cc]) = v;
      }
    }
    if (A_BF16){
      const u16* A = (const u16*)Ap;
      int rr = t >> 2, cc = (t & 3) * 8;
      int feat = k0 + cc;                       // k == feature index
      int slice = feat >> 4, off = feat & 15;   // off in {0,8}: 8-u16 load never crosses chunk
      #pragma unroll
      for (int it = 0; it < 2; ++it){
        int rl = rr + it * 64, row = row0 + rl;
        uint4 v = make_uint4(0u, 0u, 0u, 0u);
        if (row < N) v = *(const uint4*)(A + ((size_t)slice * N + row) * 16 + off);
        *(uint4*)(&As[rl * LDA + cc]) = v;
      }
    } else {
      const float* A = (const float*)Ap;
      int rr = t >> 3, cc = (t & 7) * 4;
      #pragma unroll
      for (int it = 0; it < 4; ++it){
        int rl = rr + it * 32, row = row0 + rl;
        float4 v = make_float4(0.f, 0.f, 0.f, 0.f);
        if (row < N) v = *(const float4*)(A + (size_t)row * K + k0 + cc);
        uint2 p;
        p.x = (u32)f2bf(v.x) | ((u32)f2bf(v.y) << 16);
        p.y = (u32)f2bf(v.z) | ((u32)f2bf(v.w) << 16);
        *(uint2*)(&As[rl * LDA + cc]) = p;
      }
    }
    __syncthreads();
    bf16x8 af[2], bfr[8];
    #pragma unroll
    for (int rt = 0; rt < 2; ++rt)
      af[rt] = *(const bf16x8*)(&As[(wave * 32 + rt * 16 + r) * LDA + q * 8]);
    #pragma unroll
    for (int ct = 0; ct < 8; ++ct)
      bfr[ct] = *(const bf16x8*)(&Bs[(ct * 16 + r) * LDA + q * 8]);
    #pragma unroll
    for (int rt = 0; rt < 2; ++rt)
      #pragma unroll
      for (int ct = 0; ct < 8; ++ct)
        acc[rt][ct] = __builtin_amdgcn_mfma_f32_16x16x32_bf16(af[rt], bfr[ct], acc[rt][ct], 0, 0, 0);
    __syncthreads();
  }
  // slice-major store: feat = ct*16 + r -> slice ct, offset r
  #pragma unroll
  for (int rt = 0; rt < 2; ++rt)
    #pragma unroll
    for (int reg = 0; reg < 4; ++reg){
      int row = row0 + wave * 32 + rt * 16 + q * 4 + reg;
      if (row < N)
        #pragma unroll
        for (int ct = 0; ct < 8; ++ct)
          C[((size_t)ct * N + row) * 16 + r] = f2bf(acc[rt][ct][reg]);
    }
}

// ---------------- feature-sliced edge aggregation (slice-major h) ----------------
// Wave = 1 node; 64 lanes = 8 edge-groups x 8 u32-lanes. Slice = blockIdx/nodeBlocks
// so one 3.2 MB contiguous slice is hot in every XCD's L2 at a time.
__global__ __launch_bounds__(256)
void agg_kernel(const u16* __restrict__ h, const int* __restrict__ srcs,
                const int* __restrict__ rowptr, const float* __restrict__ dinv,
                const float* __restrict__ bias, u16* __restrict__ out,
                int N, int nodeBlocks)
{
  int slice = blockIdx.x / nodeBlocks;
  int nb    = blockIdx.x - slice * nodeBlocks;
  int node  = nb * 4 + (int)(threadIdx.x >> 6);
  if (node >= N) return;
  const int lane = threadIdx.x & 63;
  const int grp = lane >> 3;          // edge group 0..7
  const int sub = lane & 7;           // u32 within 32B slice chunk
  const u32* __restrict__ hp = (const u32*)h;
  const size_t sBase = (size_t)slice * N;   // in 16-u16 (=8-u32) units
  int beg = rowptr[node], end = rowptr[node + 1];

  float ax = 0.f, ay = 0.f;
  if (beg < end){
    // pipeline: src/w one step ahead
    int e = beg + grp;
    int srcCur = __builtin_nontemporal_load(&srcs[e < end ? e : end - 1]);
    float wCur = (e < end) ? dinv[srcCur] : 0.f;
    for (int base = beg; base < end; base += 8){
      int en = base + 8 + grp;
      int srcNxt = 0;
      bool more = (base + 8 < end);
      if (more) srcNxt = __builtin_nontemporal_load(&srcs[en < end ? en : end - 1]);
      u32 v = hp[(sBase + (size_t)srcCur) * 8 + sub];   // L2-resident contiguous slice
      float wNxt = (more && en < end) ? dinv[srcNxt] : 0.f;
      ax = fmaf(wCur, bflo(v), ax);
      ay = fmaf(wCur, bfhi(v), ay);
      srcCur = srcNxt; wCur = wNxt;
    }
  }
  // reduce the 8 edge-groups (lanes with equal sub)
  #pragma unroll
  for (int off = 8; off < 64; off <<= 1){
    ax += __shfl_xor(ax, off, 64);
    ay += __shfl_xor(ay, off, 64);
  }
  if (grp == 0){
    float dv = dinv[node], dv2 = dv * dv;
    u32 hs = hp[(sBase + (size_t)node) * 8 + sub];
    float b0 = bias[slice * 16 + sub * 2 + 0], b1v = bias[slice * 16 + sub * 2 + 1];
    ax = fmaf(dv, ax, fmaf(dv2, bflo(hs), b0));
    ay = fmaf(dv, ay, fmaf(dv2, bfhi(hs), b1v));
    ax = fmaxf(ax, 0.f); ay = fmaxf(ay, 0.f);
    u32 pk = (u32)f2bf(ax) | ((u32)f2bf(ay) << 16);
    __builtin_nontemporal_store(pk, (u32*)out + (sBase + (size_t)node) * 8 + sub);
  }
}

// ---------------- per-graph max pool (slice-major h) ----------------
__global__ void pool_kernel(const u16* __restrict__ h, const int* __restrict__ batch,
                            float* __restrict__ g, int N)
{
  int graph = blockIdx.x >> 3, chunk = blockIdx.x & 7;
  int f = threadIdx.x;
  int slice = f >> 4, off = f & 15;
  int lo = 0, hi = N;
  while (lo < hi){ int mid = (lo + hi) >> 1; if (batch[mid] < graph) lo = mid + 1; else hi = mid; }
  int s = lo;
  hi = N;
  while (lo < hi){ int mid = (lo + hi) >> 1; if (batch[mid] < graph + 1) lo = mid + 1; else hi = mid; }
  int epos = lo;
  int len = epos - s;
  if (len <= 0) return;
  int per = (len + 7) >> 3;
  int a = s + chunk * per;
  int b = a + per; if (b > epos) b = epos;
  float m = 0.f;
  for (int n = a; n < b; ++n)
    m = fmaxf(m, __uint_as_float(((u32)h[((size_t)slice * N + n) * 16 + off]) << 16));
  if (a < b) atomicMax((int*)&g[graph * 128 + f], __float_as_int(m));
}

// ---------------- head ----------------
__global__ void head_kernel(const float* __restrict__ g, const float* __restrict__ Wc,
                            const float* __restrict__ bc, float* __restrict__ out)
{
  int gg = threadIdx.x;
  if (gg >= NG) return;
  float l0 = bc[0], l1 = bc[1];
  for (int f = 0; f < 128; ++f){
    float v = g[gg * 128 + f];
    l0 = fmaf(v, Wc[f * 2 + 0], l0);
    l1 = fmaf(v, Wc[f * 2 + 1], l1);
  }
  float m = fmaxf(l0, l1);
  float lse = m + logf(__expf(l0 - m) + __expf(l1 - m));
  out[gg * 2 + 0] = l0 - lse;
  out[gg * 2 + 1] = l1 - lse;
}

extern "C" void kernel_launch(void* const* d_in, const int* in_sizes, int n_in,
                              void* d_out, int out_size, void* d_ws, size_t ws_size,
                              hipStream_t stream)
{
  const float* x   = (const float*)d_in[0];
  const int*   ei  = (const int*)  d_in[1];
  const int*  batch= (const int*)  d_in[2];
  const float* W1  = (const float*)d_in[3];
  const float* b1  = (const float*)d_in[4];
  const float* W2  = (const float*)d_in[5];
  const float* b2  = (const float*)d_in[6];
  const float* Wc  = (const float*)d_in[7];
  const float* bc  = (const float*)d_in[8];
  float* out = (float*)d_out;
  (void)n_in; (void)out_size; (void)ws_size;

  const int N = in_sizes[0] / 512;
  const int E = in_sizes[1] / 2;
  const int NBK = (N + 127) >> 7;

  char* w = (char*)d_ws;
  size_t o = 0;
  auto take = [&](size_t bytes)->char* {
    char* p = w + o; o = (o + bytes + 511) & ~(size_t)511; return p;
  };
  size_t hbytes = (size_t)N * 128 * 2;
  size_t mbytes = (size_t)E * 8;
  int*   bhist  = (int*)  take((size_t)(NBK + 2) * PAD * 4);
  int*   bbase  = (int*)  take((size_t)(NBK + 2) * PAD * 4);
  int*   gcur   = (int*)  take((size_t)(NBK + 2) * PAD * 4);
  int*   rowptr = (int*)  take((size_t)(N + 1) * 4);
  float* dinv   = (float*)take((size_t)N * 4);
  int*   fin    = (int*)  take((size_t)E * 4);
  u16*   W1T    = (u16*)  take((size_t)512 * 128 * 2);
  u16*   W2T    = (u16*)  take((size_t)128 * 128 * 2);
  u16*   hA     = (u16*)  take(hbytes > mbytes ? hbytes : mbytes);
  u16*   hB     = (u16*)  take(hbytes);
  float* gpool  = (float*)take((size_t)NG * 128 * 4);
  int2*  mid    = (int2*)hA;   // mid dead before gemm1 writes hA

  hipMemsetAsync(bhist, 0, (size_t)(NBK + 2) * PAD * 4, stream);
  hipMemsetAsync(gpool, 0, (size_t)NG * 128 * 4, stream);

  bhist_kernel<<<256, 256, 0, stream>>>(ei, bhist, E, NBK);
  bscan_kernel<<<1, 256, 0, stream>>>(bhist, bbase, gcur, rowptr, NBK, E, N);
  bin_kernel<<<(E + 8191) / 8192, 256, 0, stream>>>(ei, gcur, mid, E, NBK);
  nodestat_kernel<<<NBK, 256, 0, stream>>>(mid, bbase, rowptr, dinv, N);
  scatter_kernel<<<NBK, 256, 0, stream>>>(mid, bbase, rowptr, fin, N);
  wcvt_kernel<<<256, 256, 0, stream>>>(W1, W2, W1T, W2T);

  const int GB = (N + 127) / 128;
  const int nodeBlocks = (N + 3) / 4;
  gemm_kernel<0><<<GB, 256, 0, stream>>>((const void*)x,  W1T, hA, N, 512);
  agg_kernel<<<8 * nodeBlocks, 256, 0, stream>>>(hA, fin, rowptr, dinv, b1, hB, N, nodeBlocks);
  gemm_kernel<1><<<GB, 256, 0, stream>>>((const void*)hB, W2T, hA, N, 128);
  agg_kernel<<<8 * nodeBlocks, 256, 0, stream>>>(hA, fin, rowptr, dinv, b2, hB, N, nodeBlocks);
  pool_kernel<<<NG * 8, 128, 0, stream>>>(hB, batch, gpool, N);
  head_kernel<<<1, 64, 0, stream>>>(gpool, Wc, bc, out);
}